// Round 8
// baseline (148.818 us; speedup 1.0000x reference)
//
#include <hip/hip_runtime.h>

typedef short short8 __attribute__((ext_vector_type(8)));
typedef float f32x4 __attribute__((ext_vector_type(4)));

// ---- problem constants ----
// B=16, C=1024, H=W=64, nodes 32x32, N=1024, HID=16
// d_out float offsets
#define ZOFF   16777216   // z   (B*N*HID = 262144)  == mu flat (with bias)
#define ZHOFF  17039360   // z_hat (262144)          == log_var temp, then z_hat
#define KLOFF  17301504   // kl scalar
#define DLOFF  17301505   // dl (16)
// d_out ushort offsets (scratch inside LA region, dead before la_kernel)
#define APK_U  16777216   // Apk bf16 [9][32][64][8] = 147,456
#define LVPK_U 16924672   // lvpk bf16 [32][64][8] = 16,384
// ws float offsets
#define AD_W   0          // Ad[B*N] = 16384
#define DIS_W  16384      // dis[B*N]
#define PART_W 32768      // 256 blocks x 4 floats: sigma,kl,lg partials
#define GAM_W  34816      // gamma[16]

__device__ __forceinline__ unsigned short f2bf(float f) {
    unsigned int u = __float_as_uint(f);
    unsigned int r = (u + 0x7fffu + ((u >> 16) & 1u)) >> 16;
    return (unsigned short)r;
}

// ---- K1: fused 2x2 mean pool + transpose (+ weight prep in blocks <640) ----
__global__ __launch_bounds__(256) void pool_tr_kernel(const float* __restrict__ f,
        unsigned short* __restrict__ nT, const float* __restrict__ mu_w,
        const float* __restrict__ lv_w, unsigned short* __restrict__ apk,
        unsigned short* __restrict__ lvpk)
{
    __shared__ float pls[64 * 35];
    int blk = blockIdx.x;
    int b  = blk >> 9;
    int y  = (blk >> 4) & 31;
    int cb = blk & 15;
    int t  = threadIdx.x;
    int rr  = (t >> 4) & 1;
    int c16 = t & 15;
    int cho = t >> 5;
    #pragma unroll
    for (int k = 0; k < 8; ++k) {
        int ch = (k << 3) + cho;
        float4 v = ((const float4*)f)[
            ((((b << 10) + (cb << 6) + ch) << 6) + (y << 1) + rr) * 16 + c16];
        float h0 = v.x + v.y, h1 = v.z + v.w;
        float g0 = h0 + __shfl_xor(h0, 16);
        float g1 = h1 + __shfl_xor(h1, 16);
        if (rr == 0) {
            pls[ch * 35 + (c16 << 1)]     = 0.25f * g0;
            pls[ch * 35 + (c16 << 1) + 1] = 0.25f * g1;
        }
    }
    __syncthreads();
    int px = t >> 3, cg2 = t & 7;
    unsigned short o8[8];
    #pragma unroll
    for (int i = 0; i < 8; ++i) o8[i] = f2bf(pls[((cg2 << 3) + i) * 35 + px]);
    int ofs = ((((b << 10) + (y << 5) + px)) << 10) + (cb << 6) + (cg2 << 3);
    *(short8*)&nT[ofs] = *(short8*)o8;

    if (blk < 640) {                          // fused weight prep
        int idx = blk * 256 + t;
        if (idx < 147456) {
            int tap = idx >> 14;
            int rem = idx & 16383;
            int ks = rem >> 9;
            int lane = (rem >> 3) & 63;
            int j = idx & 7;
            int o = lane & 15;
            int cc = (ks << 5) + ((lane >> 4) << 3) + j;
            apk[idx] = f2bf(mu_w[((o << 10) + cc) * 9 + tap]);
        } else {
            int i2 = idx - 147456;
            int ks = i2 >> 9;
            int lane = (i2 >> 3) & 63;
            int j = i2 & 7;
            int o = lane & 15;
            int cc = (ks << 5) + ((lane >> 4) << 3) + j;
            lvpk[i2] = f2bf(lv_w[(o << 10) + cc]);
        }
    }
}

// ---- K2: fused MFMA conv (full K) + stats epilogue -------------------------
// grid 256 = b(16) x ytile(16: 2 rows); block 256 = 4 waves (2 rows x 2 x-half)
// 32 k-steps of 32 ch; reg-prefetch staging; epilogue: bias, z/lv, Ad, partials
__global__ __launch_bounds__(256) void convstats_kernel(
        const unsigned short* __restrict__ nT,
        const unsigned short* __restrict__ apk, const unsigned short* __restrict__ lvpk,
        const float* __restrict__ mu_b, const float* __restrict__ lv_b,
        float* __restrict__ z, float* __restrict__ lvout, float* __restrict__ ws)
{
    __shared__ unsigned short st[4 * 34 * 40];   // [row 4][xx 34][ch-pad 40]
    __shared__ float red[3][4];
    int blk = blockIdx.x;
    int b  = blk >> 4;
    int yt = blk & 15;
    int y0 = yt << 1;
    int t  = threadIdx.x;
    int w  = t >> 6, l = t & 63;
    int ry = w >> 1, xh = w & 1;
    int px = l & 15, chg = l >> 4;
    f32x4 accm = {0,0,0,0}, accv = {0,0,0,0};

    if (t < 32) {                                 // x-halo zeros: 4 rows x 2 x 4
        int row = t >> 3, side = (t >> 2) & 1, quarter = t & 3;
        short8 zz = {0,0,0,0,0,0,0,0};
        *(short8*)&st[(row * 34 + side * 33) * 40 + quarter * 8] = zz;
    }

    const unsigned short* nb = nT + ((size_t)b << 20);
    // staging coords: chunk q -> row=q>>7, x=(q>>2)&31, quarter=q&3
    int qr0 = t >> 7,   qx0 = (t >> 2) & 31,  qq0 = t & 3;
    int qr1 = qr0 + 2,  qx1 = qx0,            qq1 = qq0;   // q1 = t+256
    int yin0 = y0 - 1 + qr0, yin1 = y0 - 1 + qr1;
    bool ok0 = (yin0 >= 0 && yin0 < 32), ok1 = (yin1 >= 0 && yin1 < 32);
    const short8 z8 = {0,0,0,0,0,0,0,0};
    short8 r0 = z8, r1 = z8;
    {   // prologue: issue k-step 0 loads
        int cs = 0;
        if (ok0) r0 = *(const short8*)&nb[(((yin0 << 5) + qx0) << 10) + cs + qq0 * 8];
        if (ok1) r1 = *(const short8*)&nb[(((yin1 << 5) + qx1) << 10) + cs + qq1 * 8];
    }

    for (int s = 0; s < 32; ++s) {
        __syncthreads();                          // prev compute done reading LDS
        *(short8*)&st[(qr0 * 34 + qx0 + 1) * 40 + qq0 * 8] = r0;
        *(short8*)&st[(qr1 * 34 + qx1 + 1) * 40 + qq1 * 8] = r1;
        __syncthreads();
        if (s < 31) {                             // prefetch next k-step
            int cs = (s + 1) << 5;
            r0 = z8; r1 = z8;
            if (ok0) r0 = *(const short8*)&nb[(((yin0 << 5) + qx0) << 10) + cs + qq0 * 8];
            if (ok1) r1 = *(const short8*)&nb[(((yin1 << 5) + qx1) << 10) + cs + qq1 * 8];
        }
        short8 bw[9], bvw;
        #pragma unroll
        for (int tap = 0; tap < 9; ++tap)
            bw[tap] = *(const short8*)&apk[((tap << 5) + s) * 512 + l * 8];
        bvw = *(const short8*)&lvpk[(s << 9) + l * 8];
        short8 actr;
        #pragma unroll
        for (int ky = 0; ky < 3; ++ky) {
            int row = ry + ky;
            #pragma unroll
            for (int kx = 0; kx < 3; ++kx) {
                int xx = (xh << 4) + px + kx;
                short8 a = *(const short8*)&st[(row * 34 + xx) * 40 + chg * 8];
                if (ky == 1 && kx == 1) actr = a;
                accm = __builtin_amdgcn_mfma_f32_16x16x32_bf16(a, bw[ky*3+kx], accm, 0, 0, 0);
            }
        }
        accv = __builtin_amdgcn_mfma_f32_16x16x32_bf16(actr, bvw, accv, 0, 0, 0);
    }

    // ---- stats epilogue. Lane holds D[pos=chg*4+j][o=px] ----
    float mb = mu_b[px], lb = lv_b[px];
    f32x4 mu4, lv4, sq;
    float klp = 0.f;
    #pragma unroll
    for (int j = 0; j < 4; ++j) {
        mu4[j] = accm[j] + mb;
        lv4[j] = accv[j] + lb;
        sq[j]  = mu4[j] * mu4[j];
        klp   += 1.0f + 2.0f * lv4[j] - sq[j] - expf(2.0f * lv4[j]);
    }
    // z / lv stores
    int xpos = (xh << 4) + (chg << 2);
    int nodeb = ((y0 + ry) << 5) + xpos;          // node for j=0
    int zb = (b << 14);
    #pragma unroll
    for (int j = 0; j < 4; ++j) {
        z[zb + ((nodeb + j) << 4) + px]     = mu4[j];
        lvout[zb + ((nodeb + j) << 4) + px] = lv4[j];
    }
    // Ad[pos] = sum over o: butterfly over lane bits 0..3 (o = l&15)
    #pragma unroll
    for (int m = 1; m < 16; m <<= 1) {
        #pragma unroll
        for (int j = 0; j < 4; ++j) sq[j] += __shfl_xor(sq[j], m);
    }
    float sgc = 0.f, lgc = 0.f;
    if (px == 0) {
        *(f32x4*)&ws[AD_W + (b << 10) + nodeb] = sq;
        #pragma unroll
        for (int j = 0; j < 4; ++j) {
            sgc += sq[j];
            lgc += logf(sq[j] + 1e-7f);
        }
    }
    #pragma unroll
    for (int off = 32; off > 0; off >>= 1) {
        sgc += __shfl_down(sgc, off);
        klp += __shfl_down(klp, off);
        lgc += __shfl_down(lgc, off);
    }
    if (l == 0) { red[0][w] = sgc; red[1][w] = klp; red[2][w] = lgc; }
    __syncthreads();
    if (t == 0) {
        ws[PART_W + (blk << 2) + 0] = red[0][0] + red[0][1] + red[0][2] + red[0][3];
        ws[PART_W + (blk << 2) + 1] = red[1][0] + red[1][1] + red[1][2] + red[1][3];
        ws[PART_W + (blk << 2) + 2] = red[2][0] + red[2][1] + red[2][2] + red[2][3];
    }
}

// ---- K3: deg row sums -> dis; fused gamma / z_hat / kl / dl ----------------
__global__ __launch_bounds__(256) void deg_kernel(const float* __restrict__ z,
        float* __restrict__ lvzh, float* __restrict__ ws, float* __restrict__ out)
{
    __shared__ float psum[16][17];
    __shared__ float redk[4], redl[4], fin[2];
    int b  = blockIdx.x >> 6;
    int n0 = (blockIdx.x & 63) * 16;
    int t  = threadIdx.x;
    int nl = t & 15;
    int mg = t >> 4;
    float sg16 = 0.f;
    #pragma unroll
    for (int g = 0; g < 16; ++g) sg16 += ws[PART_W + (((b << 4) + g) << 2)];
    float gam = sqrtf(1.0f + 1024.0f / (sg16 + 1e-7f));
    const float* zb = z + (b << 14);
    const float4* a4 = (const float4*)(zb + (n0 + nl) * 16);
    float4 a0 = a4[0], a1 = a4[1], a2 = a4[2], a3 = a4[3];
    float rs = 0.f;
    const float4* m4 = (const float4*)(zb + (mg << 6) * 16);
    for (int m = 0; m < 64; ++m) {
        float4 s0 = m4[m*4], s1 = m4[m*4+1], s2 = m4[m*4+2], s3 = m4[m*4+3];
        float d = a0.x*s0.x + a0.y*s0.y + a0.z*s0.z + a0.w*s0.w
                + a1.x*s1.x + a1.y*s1.y + a1.z*s1.z + a1.w*s1.w
                + a2.x*s2.x + a2.y*s2.y + a2.z*s2.z + a2.w*s2.w
                + a3.x*s3.x + a3.y*s3.y + a3.z*s3.z + a3.w*s3.w;
        rs += fmaxf(d, 0.f);
    }
    psum[mg][nl] = rs;
    __syncthreads();
    if (t < 16) {
        float total = 0.f;
        #pragma unroll
        for (int gg = 0; gg < 16; ++gg) total += psum[gg][t];
        int n = n0 + t;
        float deg = total + gam * ws[AD_W + (b << 10) + n] + 1.0f;
        ws[DIS_W + (b << 10) + n] = rsqrtf(deg + 1e-5f);
    }
    int zi = (b << 14) + ((n0 + (t >> 4)) << 4) + (t & 15);
    lvzh[zi] = gam * z[zi] * (1.0f - lvzh[zi]);
    if (blockIdx.x == 0) {
        float kl = ws[PART_W + (t << 2) + 1];
        float lg = ws[PART_W + (t << 2) + 2];
        #pragma unroll
        for (int off = 32; off > 0; off >>= 1) {
            kl += __shfl_down(kl, off);
            lg += __shfl_down(lg, off);
        }
        if ((t & 63) == 0) { redk[t >> 6] = kl; redl[t >> 6] = lg; }
        __syncthreads();
        if (t == 0) {
            fin[0] = redk[0] + redk[1] + redk[2] + redk[3];
            fin[1] = redl[0] + redl[1] + redl[2] + redl[3];
            out[KLOFF] = -0.5f * fin[0];
        }
        __syncthreads();
        if (t < 16) {
            float s = 0.f;
            #pragma unroll
            for (int g = 0; g < 16; ++g) s += ws[PART_W + (((t << 4) + g) << 2)];
            float gm = sqrtf(1.0f + 1024.0f / (s + 1e-7f));
            ws[GAM_W + t] = gm;
            out[DLOFF + t] = -gm * fin[1] / 16777216.0f;
        }
    }
}

// ---- K4: LA[b,n,m] = dis_n * dis_m * A  (contig loads, pad-17 LDS) ---------
__global__ __launch_bounds__(256) void la_kernel(const float* __restrict__ z,
        const float* __restrict__ ws, float* __restrict__ LA)
{
    __shared__ float4 za_s[16 * 17];   // [g=jj*4+kk][slot], stride 17
    __shared__ float4 zbm_s[16 * 17];
    __shared__ float dan[64], dbm[64];
    int b    = blockIdx.x >> 8;
    int tile = blockIdx.x & 255;
    int n0 = (tile >> 4) * 64;
    int m0 = (tile & 15) * 64;
    int t  = threadIdx.x;
    const float4* zsrc = (const float4*)(z + (b << 14));
    {
        int g   = (((t >> 2) & 3) << 2) + (t & 3);   // jj*4 + kk
        int slt = t >> 4;
        za_s[g * 17 + slt]  = zsrc[(n0 << 2) + t];   // 1KB contiguous load
        zbm_s[g * 17 + slt] = zsrc[(m0 << 2) + t];
    }
    const float* dis = ws + DIS_W + (b << 10);
    if (t < 64)       dan[t]      = dis[n0 + t];
    else if (t < 128) dbm[t - 64] = dis[m0 + (t - 64)];
    __syncthreads();
    int ri = t >> 4;
    int cj = t & 15;
    float acc[4][4] = {{0.f,0.f,0.f,0.f},{0.f,0.f,0.f,0.f},
                       {0.f,0.f,0.f,0.f},{0.f,0.f,0.f,0.f}};
    #pragma unroll
    for (int kk = 0; kk < 4; ++kk) {
        float4 av[4], bv[4];
        #pragma unroll
        for (int i = 0; i < 4; ++i) av[i] = za_s[((i << 2) + kk) * 17 + ri];
        #pragma unroll
        for (int j = 0; j < 4; ++j) bv[j] = zbm_s[((j << 2) + kk) * 17 + cj];
        #pragma unroll
        for (int i = 0; i < 4; ++i)
            #pragma unroll
            for (int j = 0; j < 4; ++j)
                acc[i][j] += av[i].x * bv[j].x + av[i].y * bv[j].y
                           + av[i].z * bv[j].z + av[i].w * bv[j].w;
    }
    float g = ws[GAM_W + b];
    const float* Ad = ws + AD_W + (b << 10);
    #pragma unroll
    for (int i = 0; i < 4; ++i) {
        int n = n0 + ri * 4 + i;
        float dn = dan[ri * 4 + i];
        float4 o;
        float* op = &o.x;
        #pragma unroll
        for (int j = 0; j < 4; ++j) {
            int m = m0 + cj * 4 + j;
            float v = fmaxf(acc[i][j], 0.f);
            if (n == m) v += g * Ad[n] + 1.0f;
            op[j] = dn * dbm[cj * 4 + j] * v;
        }
        *(float4*)(LA + ((size_t)b << 20) + ((size_t)n << 10) + m0 + cj * 4) = o;
    }
}

extern "C" void kernel_launch(void* const* d_in, const int* in_sizes, int n_in,
                              void* d_out, int out_size, void* d_ws, size_t ws_size,
                              hipStream_t stream) {
    const float* feature = (const float*)d_in[0];
    const float* mu_w    = (const float*)d_in[1];
    const float* mu_b    = (const float*)d_in[2];
    const float* lv_w    = (const float*)d_in[3];
    const float* lv_b    = (const float*)d_in[4];
    float* out = (float*)d_out;
    float* ws  = (float*)d_ws;
    unsigned short* nT   = (unsigned short*)d_out;          // LA region scratch
    unsigned short* apk  = nT + APK_U;
    unsigned short* lvpk = nT + LVPK_U;

    pool_tr_kernel<<<8192, 256, 0, stream>>>(feature, nT, mu_w, lv_w, apk, lvpk);
    convstats_kernel<<<256, 256, 0, stream>>>(nT, apk, lvpk, mu_b, lv_b,
                                              out + ZOFF, out + ZHOFF, ws);
    deg_kernel<<<1024, 256, 0, stream>>>(out + ZOFF, out + ZHOFF, ws, out);
    la_kernel<<<4096, 256, 0, stream>>>(out + ZOFF, ws, out);
}

// Round 11
// 132.426 us; speedup vs baseline: 1.1238x; 1.1238x over previous
//
#include <hip/hip_runtime.h>

typedef short short8 __attribute__((ext_vector_type(8)));
typedef float f32x4 __attribute__((ext_vector_type(4)));
typedef unsigned short ushort4v __attribute__((ext_vector_type(4)));

// ---- problem constants ----
// B=16, C=1024, H=W=64, nodes 32x32, N=1024, HID=16
// d_out float offsets
#define ZOFF   16777216   // z   (B*N*HID = 262144)  == mu flat (with bias)
#define ZHOFF  17039360   // z_hat (262144)          == log_var temp, then z_hat
#define KLOFF  17301504   // kl scalar
#define DLOFF  17301505   // dl (16)
// d_out ushort offsets (scratch inside LA region, dead before la_kernel)
#define APK_U  16777216   // Apk bf16 [9][32][64][8] = 147,456
#define LVPK_U 16924672   // lvpk bf16 [32][64][8] = 16,384
// ws float offsets
#define AD_W   0          // Ad[B*N] = 16384
#define DIS_W  16384      // dis[B*N]
#define PART_W 32768      // 256 blocks x 4 floats: sigma,kl,lg partials
#define GAM_W  34816      // gamma[16]
#define PMU_W  65536      // mu partials bf16 [8][16][16][1024] (ushort idx base)
#define PLV_W  2162688    // lv partials bf16, same shape

__device__ __forceinline__ unsigned short f2bf(float f) {
    unsigned int u = __float_as_uint(f);
    unsigned int r = (u + 0x7fffu + ((u >> 16) & 1u)) >> 16;
    return (unsigned short)r;
}
__device__ __forceinline__ float bf2f(unsigned short u) {
    return __uint_as_float(((unsigned int)u) << 16);
}

// ---- K1: fused 2x2 mean pool + transpose (+ weight prep in blocks <640) ----
__global__ __launch_bounds__(256) void pool_tr_kernel(const float* __restrict__ f,
        unsigned short* __restrict__ nT, const float* __restrict__ mu_w,
        const float* __restrict__ lv_w, unsigned short* __restrict__ apk,
        unsigned short* __restrict__ lvpk)
{
    __shared__ float pls[64 * 35];
    int blk = blockIdx.x;
    int b  = blk >> 9;
    int y  = (blk >> 4) & 31;
    int cb = blk & 15;
    int t  = threadIdx.x;
    int rr  = (t >> 4) & 1;
    int c16 = t & 15;
    int cho = t >> 5;
    #pragma unroll
    for (int k = 0; k < 8; ++k) {
        int ch = (k << 3) + cho;
        float4 v = ((const float4*)f)[
            ((((b << 10) + (cb << 6) + ch) << 6) + (y << 1) + rr) * 16 + c16];
        float h0 = v.x + v.y, h1 = v.z + v.w;
        float g0 = h0 + __shfl_xor(h0, 16);
        float g1 = h1 + __shfl_xor(h1, 16);
        if (rr == 0) {
            pls[ch * 35 + (c16 << 1)]     = 0.25f * g0;
            pls[ch * 35 + (c16 << 1) + 1] = 0.25f * g1;
        }
    }
    __syncthreads();
    int px = t >> 3, cg2 = t & 7;
    unsigned short o8[8];
    #pragma unroll
    for (int i = 0; i < 8; ++i) o8[i] = f2bf(pls[((cg2 << 3) + i) * 35 + px]);
    int ofs = ((((b << 10) + (y << 5) + px)) << 10) + (cb << 6) + (cg2 << 3);
    *(short8*)&nT[ofs] = *(short8*)o8;

    if (blk < 640) {                          // fused weight prep
        int idx = blk * 256 + t;
        if (idx < 147456) {
            int tap = idx >> 14;
            int rem = idx & 16383;
            int ks = rem >> 9;
            int lane = (rem >> 3) & 63;
            int j = idx & 7;
            int o = lane & 15;
            int cc = (ks << 5) + ((lane >> 4) << 3) + j;
            apk[idx] = f2bf(mu_w[((o << 10) + cc) * 9 + tap]);
        } else {
            int i2 = idx - 147456;
            int ks = i2 >> 9;
            int lane = (i2 >> 3) & 63;
            int j = i2 & 7;
            int o = lane & 15;
            int cc = (ks << 5) + ((lane >> 4) << 3) + j;
            lvpk[i2] = f2bf(lv_w[(o << 10) + cc]);
        }
    }
}

// ---- K2: MFMA conv split-K partials (bf16 out): mu (3x3 SAME) + lv (1x1) ----
// grid 1024 = b(16) x ytile(8: 4 rows) x kchunk(8: 128 ch); block 256 = 4 waves
__global__ __launch_bounds__(256) void conv_mfma(const unsigned short* __restrict__ nT,
        const unsigned short* __restrict__ apk, const unsigned short* __restrict__ lvpk,
        unsigned short* __restrict__ pmu, unsigned short* __restrict__ plv)
{
    __shared__ unsigned short st[6 * 34 * 40];   // stride 80B = 5 quads
    int blk = blockIdx.x;
    int b  = blk >> 6;
    int yt = (blk >> 3) & 7;
    int kc = blk & 7;
    int y0 = yt << 2;
    int t  = threadIdx.x;
    int w  = t >> 6, l = t & 63;
    int px = l & 15, chg = l >> 4;
    f32x4 accm[2] = {{0,0,0,0},{0,0,0,0}};
    f32x4 accv[2] = {{0,0,0,0},{0,0,0,0}};

    if (t < 48) {                                 // x-halo zeros: 6 rows x 2 x 4
        int row = t >> 3, side = (t >> 2) & 1, quarter = t & 3;
        short8 z8 = {0,0,0,0,0,0,0,0};
        *(short8*)&st[(row * 34 + side * 33) * 40 + quarter * 8] = z8;
    }

    for (int s = 0; s < 4; ++s) {
        int ksg = (kc << 2) + s;
        int cs  = ksg << 5;
        __syncthreads();
        #pragma unroll
        for (int k2 = 0; k2 < 3; ++k2) {          // stage 6 rows x 32 x x 32 ch
            int q = t + (k2 << 8);
            int quarter = q & 3, x = (q >> 2) & 31, row = q >> 7;
            int yin = y0 - 1 + row;
            short8 v = {0,0,0,0,0,0,0,0};
            if (yin >= 0 && yin < 32)
                v = *(const short8*)&nT[(((b << 10) + (yin << 5) + x) << 10) + cs + quarter * 8];
            *(short8*)&st[(row * 34 + x + 1) * 40 + quarter * 8] = v;
        }
        __syncthreads();
        short8 bw[9], bvw;
        #pragma unroll
        for (int tap = 0; tap < 9; ++tap)
            bw[tap] = *(const short8*)&apk[((tap << 5) + ksg) * 512 + l * 8];
        bvw = *(const short8*)&lvpk[(ksg << 9) + l * 8];
        #pragma unroll
        for (int h = 0; h < 2; ++h) {
            short8 actr;
            #pragma unroll
            for (int ky = 0; ky < 3; ++ky) {
                int row = w + ky;
                #pragma unroll
                for (int kx = 0; kx < 3; ++kx) {
                    int xx = (h << 4) + px + kx;
                    short8 a = *(const short8*)&st[(row * 34 + xx) * 40 + chg * 8];
                    if (ky == 1 && kx == 1) actr = a;
                    accm[h] = __builtin_amdgcn_mfma_f32_16x16x32_bf16(a, bw[ky*3+kx], accm[h], 0, 0, 0);
                }
            }
            accv[h] = __builtin_amdgcn_mfma_f32_16x16x32_bf16(actr, bvw, accv[h], 0, 0, 0);
        }
    }
    int o = px;
    #pragma unroll
    for (int h = 0; h < 2; ++h) {
        int x = (h << 4) + (chg << 2);
        int idx = (((kc << 4) + b) << 14) + (o << 10) + ((y0 + w) << 5) + x;
        ushort4v m16, v16;
        #pragma unroll
        for (int j = 0; j < 4; ++j) { m16[j] = f2bf(accm[h][j]); v16[j] = f2bf(accv[h][j]); }
        *(ushort4v*)&pmu[idx] = m16;
        *(ushort4v*)&plv[idx] = v16;
    }
}

// ---- K3: combine split-K (bf16) + bias -> z/lv; Ad, block partials ---------
// grid 256 = b(16) x ng(16: 64 nodes)
__global__ __launch_bounds__(256) void stats_kernel(const unsigned short* __restrict__ pmu,
        const unsigned short* __restrict__ plv, const float* __restrict__ mu_b,
        const float* __restrict__ lv_b, float* __restrict__ z,
        float* __restrict__ lvout, float* __restrict__ ws)
{
    __shared__ float smu[16 * 68], slv[16 * 68];
    __shared__ float red[3][4];
    int blk = blockIdx.x;
    int b = blk >> 4, ng = blk & 15;
    int t = threadIdx.x;
    {
        int o = t >> 4, f4c = t & 15;
        int base = (b << 14) + (o << 10) + (ng << 6) + (f4c << 2);
        f32x4 m = {0,0,0,0}, lv = {0,0,0,0};
        #pragma unroll
        for (int kc = 0; kc < 8; ++kc) {
            ushort4v mu16 = *(const ushort4v*)(pmu + (kc << 18) + base);
            ushort4v lv16 = *(const ushort4v*)(plv + (kc << 18) + base);
            #pragma unroll
            for (int c = 0; c < 4; ++c) {
                m[c]  += bf2f(mu16[c]);
                lv[c] += bf2f(lv16[c]);
            }
        }
        float mb = mu_b[o], lb = lv_b[o];
        #pragma unroll
        for (int c = 0; c < 4; ++c) {
            smu[o * 68 + (f4c << 2) + c] = m[c] + mb;
            slv[o * 68 + (f4c << 2) + c] = lv[c] + lb;
        }
    }
    __syncthreads();
    int node2 = t >> 2, og = t & 3;
    f32x4 zm, zl;
    float ad = 0.f, klp = 0.f;
    #pragma unroll
    for (int c = 0; c < 4; ++c) {
        float mm = smu[((og << 2) + c) * 68 + node2];
        float ll = slv[((og << 2) + c) * 68 + node2];
        zm[c] = mm; zl[c] = ll;
        ad  += mm * mm;
        klp += 1.0f + 2.0f * ll - mm * mm - expf(2.0f * ll);
    }
    int zofs = (b << 14) + (((ng << 6) + node2) << 4) + (og << 2);
    *(f32x4*)(z + zofs)     = zm;
    *(f32x4*)(lvout + zofs) = zl;
    ad  += __shfl_xor(ad, 1);  ad  += __shfl_xor(ad, 2);
    klp += __shfl_xor(klp, 1); klp += __shfl_xor(klp, 2);
    float lg = logf(ad + 1e-7f);
    if (og == 0) ws[AD_W + (b << 10) + (ng << 6) + node2] = ad;
    float sgc = (og == 0) ? ad  : 0.f;
    float klc = (og == 0) ? klp : 0.f;
    float lgc = (og == 0) ? lg  : 0.f;
    #pragma unroll
    for (int off = 32; off > 0; off >>= 1) {
        sgc += __shfl_down(sgc, off);
        klc += __shfl_down(klc, off);
        lgc += __shfl_down(lgc, off);
    }
    int wv = t >> 6;
    if ((t & 63) == 0) { red[0][wv] = sgc; red[1][wv] = klc; red[2][wv] = lgc; }
    __syncthreads();
    if (t == 0) {
        ws[PART_W + (blk << 2) + 0] = red[0][0] + red[0][1] + red[0][2] + red[0][3];
        ws[PART_W + (blk << 2) + 1] = red[1][0] + red[1][1] + red[1][2] + red[1][3];
        ws[PART_W + (blk << 2) + 2] = red[2][0] + red[2][1] + red[2][2] + red[2][3];
    }
}

// ---- K4: deg row sums -> dis; fused gamma / z_hat / kl / dl ----------------
__global__ __launch_bounds__(256) void deg_kernel(const float* __restrict__ z,
        float* __restrict__ lvzh, float* __restrict__ ws, float* __restrict__ out)
{
    __shared__ float psum[16][17];
    __shared__ float redk[4], redl[4], fin[2];
    int b  = blockIdx.x >> 6;
    int n0 = (blockIdx.x & 63) * 16;
    int t  = threadIdx.x;
    int nl = t & 15;
    int mg = t >> 4;
    float sg16 = 0.f;
    #pragma unroll
    for (int g = 0; g < 16; ++g) sg16 += ws[PART_W + (((b << 4) + g) << 2)];
    float gam = sqrtf(1.0f + 1024.0f / (sg16 + 1e-7f));
    const float* zb = z + (b << 14);
    const float4* a4 = (const float4*)(zb + (n0 + nl) * 16);
    float4 a0 = a4[0], a1 = a4[1], a2 = a4[2], a3 = a4[3];
    float rs = 0.f;
    const float4* m4 = (const float4*)(zb + (mg << 6) * 16);
    for (int m = 0; m < 64; ++m) {
        float4 s0 = m4[m*4], s1 = m4[m*4+1], s2 = m4[m*4+2], s3 = m4[m*4+3];
        float d = a0.x*s0.x + a0.y*s0.y + a0.z*s0.z + a0.w*s0.w
                + a1.x*s1.x + a1.y*s1.y + a1.z*s1.z + a1.w*s1.w
                + a2.x*s2.x + a2.y*s2.y + a2.z*s2.z + a2.w*s2.w
                + a3.x*s3.x + a3.y*s3.y + a3.z*s3.z + a3.w*s3.w;
        rs += fmaxf(d, 0.f);
    }
    psum[mg][nl] = rs;
    __syncthreads();
    if (t < 16) {
        float total = 0.f;
        #pragma unroll
        for (int gg = 0; gg < 16; ++gg) total += psum[gg][t];
        int n = n0 + t;
        float deg = total + gam * ws[AD_W + (b << 10) + n] + 1.0f;
        ws[DIS_W + (b << 10) + n] = rsqrtf(deg + 1e-5f);
    }
    int zi = (b << 14) + ((n0 + (t >> 4)) << 4) + (t & 15);
    lvzh[zi] = gam * z[zi] * (1.0f - lvzh[zi]);
    if (blockIdx.x == 0) {
        float kl = ws[PART_W + (t << 2) + 1];
        float lg = ws[PART_W + (t << 2) + 2];
        #pragma unroll
        for (int off = 32; off > 0; off >>= 1) {
            kl += __shfl_down(kl, off);
            lg += __shfl_down(lg, off);
        }
        if ((t & 63) == 0) { redk[t >> 6] = kl; redl[t >> 6] = lg; }
        __syncthreads();
        if (t == 0) {
            fin[0] = redk[0] + redk[1] + redk[2] + redk[3];
            fin[1] = redl[0] + redl[1] + redl[2] + redl[3];
            out[KLOFF] = -0.5f * fin[0];
        }
        __syncthreads();
        if (t < 16) {
            float s = 0.f;
            #pragma unroll
            for (int g = 0; g < 16; ++g) s += ws[PART_W + (((t << 4) + g) << 2)];
            float gm = sqrtf(1.0f + 1024.0f / (s + 1e-7f));
            ws[GAM_W + t] = gm;
            out[DLOFF + t] = -gm * fin[1] / 16777216.0f;
        }
    }
}

// ---- K5: LA[b,n,m] = dis_n * dis_m * A  (contig loads, pad-17 LDS) ---------
__global__ __launch_bounds__(256) void la_kernel(const float* __restrict__ z,
        const float* __restrict__ ws, float* __restrict__ LA)
{
    __shared__ float4 za_s[16 * 17];   // [g=jj*4+kk][slot], stride 17
    __shared__ float4 zbm_s[16 * 17];
    __shared__ float dan[64], dbm[64];
    int b    = blockIdx.x >> 8;
    int tile = blockIdx.x & 255;
    int n0 = (tile >> 4) * 64;
    int m0 = (tile & 15) * 64;
    int t  = threadIdx.x;
    const float4* zsrc = (const float4*)(z + (b << 14));
    {
        int g   = (((t >> 2) & 3) << 2) + (t & 3);   // jj*4 + kk
        int slt = t >> 4;
        za_s[g * 17 + slt]  = zsrc[(n0 << 2) + t];   // 1KB contiguous load
        zbm_s[g * 17 + slt] = zsrc[(m0 << 2) + t];
    }
    const float* dis = ws + DIS_W + (b << 10);
    if (t < 64)       dan[t]      = dis[n0 + t];
    else if (t < 128) dbm[t - 64] = dis[m0 + (t - 64)];
    __syncthreads();
    int ri = t >> 4;
    int cj = t & 15;
    float acc[4][4] = {{0.f,0.f,0.f,0.f},{0.f,0.f,0.f,0.f},
                       {0.f,0.f,0.f,0.f},{0.f,0.f,0.f,0.f}};
    #pragma unroll
    for (int kk = 0; kk < 4; ++kk) {
        float4 av[4], bv[4];
        #pragma unroll
        for (int i = 0; i < 4; ++i) av[i] = za_s[((i << 2) + kk) * 17 + ri];
        #pragma unroll
        for (int j = 0; j < 4; ++j) bv[j] = zbm_s[((j << 2) + kk) * 17 + cj];
        #pragma unroll
        for (int i = 0; i < 4; ++i)
            #pragma unroll
            for (int j = 0; j < 4; ++j)
                acc[i][j] += av[i].x * bv[j].x + av[i].y * bv[j].y
                           + av[i].z * bv[j].z + av[i].w * bv[j].w;
    }
    float g = ws[GAM_W + b];
    const float* Ad = ws + AD_W + (b << 10);
    #pragma unroll
    for (int i = 0; i < 4; ++i) {
        int n = n0 + ri * 4 + i;
        float dn = dan[ri * 4 + i];
        float4 o;
        float* op = &o.x;
        #pragma unroll
        for (int j = 0; j < 4; ++j) {
            int m = m0 + cj * 4 + j;
            float v = fmaxf(acc[i][j], 0.f);
            if (n == m) v += g * Ad[n] + 1.0f;
            op[j] = dn * dbm[cj * 4 + j] * v;
        }
        *(float4*)(LA + ((size_t)b << 20) + ((size_t)n << 10) + m0 + cj * 4) = o;
    }
}

extern "C" void kernel_launch(void* const* d_in, const int* in_sizes, int n_in,
                              void* d_out, int out_size, void* d_ws, size_t ws_size,
                              hipStream_t stream) {
    const float* feature = (const float*)d_in[0];
    const float* mu_w    = (const float*)d_in[1];
    const float* mu_b    = (const float*)d_in[2];
    const float* lv_w    = (const float*)d_in[3];
    const float* lv_b    = (const float*)d_in[4];
    float* out = (float*)d_out;
    float* ws  = (float*)d_ws;
    unsigned short* nT   = (unsigned short*)d_out;          // LA region scratch
    unsigned short* apk  = nT + APK_U;
    unsigned short* lvpk = nT + LVPK_U;
    unsigned short* pmu16 = (unsigned short*)(ws + PMU_W);
    unsigned short* plv16 = (unsigned short*)(ws + PLV_W);

    pool_tr_kernel<<<8192, 256, 0, stream>>>(feature, nT, mu_w, lv_w, apk, lvpk);
    conv_mfma<<<1024, 256, 0, stream>>>(nT, apk, lvpk, pmu16, plv16);
    stats_kernel<<<256, 256, 0, stream>>>(pmu16, plv16, mu_b, lv_b,
                                          out + ZOFF, out + ZHOFF, ws);
    deg_kernel<<<1024, 256, 0, stream>>>(out + ZOFF, out + ZHOFF, ws, out);
    la_kernel<<<4096, 256, 0, stream>>>(out + ZOFF, ws, out);
}

// Round 12
// 128.434 us; speedup vs baseline: 1.1587x; 1.0311x over previous
//
#include <hip/hip_runtime.h>

typedef short short8 __attribute__((ext_vector_type(8)));
typedef float f32x4 __attribute__((ext_vector_type(4)));
typedef unsigned short ushort4v __attribute__((ext_vector_type(4)));

// ---- problem constants ----
// B=16, C=1024, H=W=64, nodes 32x32, N=1024, HID=16
// d_out float offsets
#define ZOFF   16777216   // z   (B*N*HID = 262144)  == mu flat (with bias)
#define ZHOFF  17039360   // z_hat (262144)          == log_var temp, then z_hat
#define KLOFF  17301504   // kl scalar
#define DLOFF  17301505   // dl (16)
// d_out ushort offsets (scratch inside LA region, dead before la_kernel)
#define APK_U  16777216   // Apk bf16 [9][32][64][8] = 147,456
#define LVPK_U 16924672   // lvpk bf16 [32][64][8] = 16,384
// ws float offsets
#define AD_W   0          // Ad[B*N] = 16384
#define DIS_W  16384      // dis[B*N]
#define PART_W 32768      // 256 blocks x 4 floats: sigma,kl,lg partials
#define GAM_W  34816      // gamma[16]
#define PMU_W  65536      // mu partials bf16 [8][16][16][1024] (1,048,576 floats)
#define PLV_W  2162688    // lv partials bf16, same extent
#define Z16F   3211264    // z bf16 copy [16][1024][16] = 262,144 ushorts (131,072 floats)

__device__ __forceinline__ unsigned short f2bf(float f) {
    unsigned int u = __float_as_uint(f);
    unsigned int r = (u + 0x7fffu + ((u >> 16) & 1u)) >> 16;
    return (unsigned short)r;
}
__device__ __forceinline__ float bf2f(unsigned short u) {
    return __uint_as_float(((unsigned int)u) << 16);
}

// ---- K1: fused 2x2 mean pool + transpose (+ weight prep in blocks <640) ----
__global__ __launch_bounds__(256) void pool_tr_kernel(const float* __restrict__ f,
        unsigned short* __restrict__ nT, const float* __restrict__ mu_w,
        const float* __restrict__ lv_w, unsigned short* __restrict__ apk,
        unsigned short* __restrict__ lvpk)
{
    __shared__ float pls[64 * 35];
    int blk = blockIdx.x;
    int b  = blk >> 9;
    int y  = (blk >> 4) & 31;
    int cb = blk & 15;
    int t  = threadIdx.x;
    int rr  = (t >> 4) & 1;
    int c16 = t & 15;
    int cho = t >> 5;
    #pragma unroll
    for (int k = 0; k < 8; ++k) {
        int ch = (k << 3) + cho;
        float4 v = ((const float4*)f)[
            ((((b << 10) + (cb << 6) + ch) << 6) + (y << 1) + rr) * 16 + c16];
        float h0 = v.x + v.y, h1 = v.z + v.w;
        float g0 = h0 + __shfl_xor(h0, 16);
        float g1 = h1 + __shfl_xor(h1, 16);
        if (rr == 0) {
            pls[ch * 35 + (c16 << 1)]     = 0.25f * g0;
            pls[ch * 35 + (c16 << 1) + 1] = 0.25f * g1;
        }
    }
    __syncthreads();
    int px = t >> 3, cg2 = t & 7;
    unsigned short o8[8];
    #pragma unroll
    for (int i = 0; i < 8; ++i) o8[i] = f2bf(pls[((cg2 << 3) + i) * 35 + px]);
    int ofs = ((((b << 10) + (y << 5) + px)) << 10) + (cb << 6) + (cg2 << 3);
    *(short8*)&nT[ofs] = *(short8*)o8;

    if (blk < 640) {                          // fused weight prep
        int idx = blk * 256 + t;
        if (idx < 147456) {
            int tap = idx >> 14;
            int rem = idx & 16383;
            int ks = rem >> 9;
            int lane = (rem >> 3) & 63;
            int j = idx & 7;
            int o = lane & 15;
            int cc = (ks << 5) + ((lane >> 4) << 3) + j;
            apk[idx] = f2bf(mu_w[((o << 10) + cc) * 9 + tap]);
        } else {
            int i2 = idx - 147456;
            int ks = i2 >> 9;
            int lane = (i2 >> 3) & 63;
            int j = i2 & 7;
            int o = lane & 15;
            int cc = (ks << 5) + ((lane >> 4) << 3) + j;
            lvpk[i2] = f2bf(lv_w[(o << 10) + cc]);
        }
    }
}

// ---- K2: MFMA conv split-K partials (bf16 out): mu (3x3 SAME) + lv (1x1) ----
// grid 1024 = b(16) x ytile(8: 4 rows) x kchunk(8: 128 ch); block 256 = 4 waves
__global__ __launch_bounds__(256) void conv_mfma(const unsigned short* __restrict__ nT,
        const unsigned short* __restrict__ apk, const unsigned short* __restrict__ lvpk,
        unsigned short* __restrict__ pmu, unsigned short* __restrict__ plv)
{
    __shared__ unsigned short st[6 * 34 * 40];   // stride 80B = 5 quads
    int blk = blockIdx.x;
    int b  = blk >> 6;
    int yt = (blk >> 3) & 7;
    int kc = blk & 7;
    int y0 = yt << 2;
    int t  = threadIdx.x;
    int w  = t >> 6, l = t & 63;
    int px = l & 15, chg = l >> 4;
    f32x4 accm[2] = {{0,0,0,0},{0,0,0,0}};
    f32x4 accv[2] = {{0,0,0,0},{0,0,0,0}};

    if (t < 48) {                                 // x-halo zeros: 6 rows x 2 x 4
        int row = t >> 3, side = (t >> 2) & 1, quarter = t & 3;
        short8 z8 = {0,0,0,0,0,0,0,0};
        *(short8*)&st[(row * 34 + side * 33) * 40 + quarter * 8] = z8;
    }

    for (int s = 0; s < 4; ++s) {
        int ksg = (kc << 2) + s;
        int cs  = ksg << 5;
        __syncthreads();
        #pragma unroll
        for (int k2 = 0; k2 < 3; ++k2) {          // stage 6 rows x 32 x x 32 ch
            int q = t + (k2 << 8);
            int quarter = q & 3, x = (q >> 2) & 31, row = q >> 7;
            int yin = y0 - 1 + row;
            short8 v = {0,0,0,0,0,0,0,0};
            if (yin >= 0 && yin < 32)
                v = *(const short8*)&nT[(((b << 10) + (yin << 5) + x) << 10) + cs + quarter * 8];
            *(short8*)&st[(row * 34 + x + 1) * 40 + quarter * 8] = v;
        }
        __syncthreads();
        short8 bw[9], bvw;
        #pragma unroll
        for (int tap = 0; tap < 9; ++tap)
            bw[tap] = *(const short8*)&apk[((tap << 5) + ksg) * 512 + l * 8];
        bvw = *(const short8*)&lvpk[(ksg << 9) + l * 8];
        #pragma unroll
        for (int h = 0; h < 2; ++h) {
            short8 actr;
            #pragma unroll
            for (int ky = 0; ky < 3; ++ky) {
                int row = w + ky;
                #pragma unroll
                for (int kx = 0; kx < 3; ++kx) {
                    int xx = (h << 4) + px + kx;
                    short8 a = *(const short8*)&st[(row * 34 + xx) * 40 + chg * 8];
                    if (ky == 1 && kx == 1) actr = a;
                    accm[h] = __builtin_amdgcn_mfma_f32_16x16x32_bf16(a, bw[ky*3+kx], accm[h], 0, 0, 0);
                }
            }
            accv[h] = __builtin_amdgcn_mfma_f32_16x16x32_bf16(actr, bvw, accv[h], 0, 0, 0);
        }
    }
    int o = px;
    #pragma unroll
    for (int h = 0; h < 2; ++h) {
        int x = (h << 4) + (chg << 2);
        int idx = (((kc << 4) + b) << 14) + (o << 10) + ((y0 + w) << 5) + x;
        ushort4v m16, v16;
        #pragma unroll
        for (int j = 0; j < 4; ++j) { m16[j] = f2bf(accm[h][j]); v16[j] = f2bf(accv[h][j]); }
        *(ushort4v*)&pmu[idx] = m16;
        *(ushort4v*)&plv[idx] = v16;
    }
}

// ---- K3: combine split-K (bf16) + bias -> z/lv (+z16); Ad, block partials --
// grid 256 = b(16) x ng(16: 64 nodes)
__global__ __launch_bounds__(256) void stats_kernel(const unsigned short* __restrict__ pmu,
        const unsigned short* __restrict__ plv, const float* __restrict__ mu_b,
        const float* __restrict__ lv_b, float* __restrict__ z,
        float* __restrict__ lvout, float* __restrict__ ws)
{
    __shared__ float smu[16 * 68], slv[16 * 68];
    __shared__ float red[3][4];
    unsigned short* z16 = (unsigned short*)(ws + Z16F);
    int blk = blockIdx.x;
    int b = blk >> 4, ng = blk & 15;
    int t = threadIdx.x;
    {
        int o = t >> 4, f4c = t & 15;
        int base = (b << 14) + (o << 10) + (ng << 6) + (f4c << 2);
        f32x4 m = {0,0,0,0}, lv = {0,0,0,0};
        #pragma unroll
        for (int kc = 0; kc < 8; ++kc) {
            ushort4v mu16 = *(const ushort4v*)(pmu + (kc << 18) + base);
            ushort4v lv16 = *(const ushort4v*)(plv + (kc << 18) + base);
            #pragma unroll
            for (int c = 0; c < 4; ++c) {
                m[c]  += bf2f(mu16[c]);
                lv[c] += bf2f(lv16[c]);
            }
        }
        float mb = mu_b[o], lb = lv_b[o];
        #pragma unroll
        for (int c = 0; c < 4; ++c) {
            smu[o * 68 + (f4c << 2) + c] = m[c] + mb;
            slv[o * 68 + (f4c << 2) + c] = lv[c] + lb;
        }
    }
    __syncthreads();
    int node2 = t >> 2, og = t & 3;
    f32x4 zm, zl;
    float ad = 0.f, klp = 0.f;
    #pragma unroll
    for (int c = 0; c < 4; ++c) {
        float mm = smu[((og << 2) + c) * 68 + node2];
        float ll = slv[((og << 2) + c) * 68 + node2];
        zm[c] = mm; zl[c] = ll;
        ad  += mm * mm;
        klp += 1.0f + 2.0f * ll - mm * mm - expf(2.0f * ll);
    }
    int zofs = (b << 14) + (((ng << 6) + node2) << 4) + (og << 2);
    *(f32x4*)(z + zofs)     = zm;
    *(f32x4*)(lvout + zofs) = zl;
    ushort4v z16v;
    #pragma unroll
    for (int c = 0; c < 4; ++c) z16v[c] = f2bf(zm[c]);
    *(ushort4v*)&z16[zofs] = z16v;
    ad  += __shfl_xor(ad, 1);  ad  += __shfl_xor(ad, 2);
    klp += __shfl_xor(klp, 1); klp += __shfl_xor(klp, 2);
    float lg = logf(ad + 1e-7f);
    if (og == 0) ws[AD_W + (b << 10) + (ng << 6) + node2] = ad;
    float sgc = (og == 0) ? ad  : 0.f;
    float klc = (og == 0) ? klp : 0.f;
    float lgc = (og == 0) ? lg  : 0.f;
    #pragma unroll
    for (int off = 32; off > 0; off >>= 1) {
        sgc += __shfl_down(sgc, off);
        klc += __shfl_down(klc, off);
        lgc += __shfl_down(lgc, off);
    }
    int wv = t >> 6;
    if ((t & 63) == 0) { red[0][wv] = sgc; red[1][wv] = klc; red[2][wv] = lgc; }
    __syncthreads();
    if (t == 0) {
        ws[PART_W + (blk << 2) + 0] = red[0][0] + red[0][1] + red[0][2] + red[0][3];
        ws[PART_W + (blk << 2) + 1] = red[1][0] + red[1][1] + red[1][2] + red[1][3];
        ws[PART_W + (blk << 2) + 2] = red[2][0] + red[2][1] + red[2][2] + red[2][3];
    }
}

// ---- K4: deg row sums -> dis; fused gamma / z_hat / kl / dl ----------------
__global__ __launch_bounds__(256) void deg_kernel(const float* __restrict__ z,
        float* __restrict__ lvzh, float* __restrict__ ws, float* __restrict__ out)
{
    __shared__ float psum[16][17];
    __shared__ float redk[4], redl[4], fin[2];
    int b  = blockIdx.x >> 6;
    int n0 = (blockIdx.x & 63) * 16;
    int t  = threadIdx.x;
    int nl = t & 15;
    int mg = t >> 4;
    float sg16 = 0.f;
    #pragma unroll
    for (int g = 0; g < 16; ++g) sg16 += ws[PART_W + (((b << 4) + g) << 2)];
    float gam = sqrtf(1.0f + 1024.0f / (sg16 + 1e-7f));
    const float* zb = z + (b << 14);
    const float4* a4 = (const float4*)(zb + (n0 + nl) * 16);
    float4 a0 = a4[0], a1 = a4[1], a2 = a4[2], a3 = a4[3];
    float rs = 0.f;
    const float4* m4 = (const float4*)(zb + (mg << 6) * 16);
    for (int m = 0; m < 64; ++m) {
        float4 s0 = m4[m*4], s1 = m4[m*4+1], s2 = m4[m*4+2], s3 = m4[m*4+3];
        float d = a0.x*s0.x + a0.y*s0.y + a0.z*s0.z + a0.w*s0.w
                + a1.x*s1.x + a1.y*s1.y + a1.z*s1.z + a1.w*s1.w
                + a2.x*s2.x + a2.y*s2.y + a2.z*s2.z + a2.w*s2.w
                + a3.x*s3.x + a3.y*s3.y + a3.z*s3.z + a3.w*s3.w;
        rs += fmaxf(d, 0.f);
    }
    psum[mg][nl] = rs;
    __syncthreads();
    if (t < 16) {
        float total = 0.f;
        #pragma unroll
        for (int gg = 0; gg < 16; ++gg) total += psum[gg][t];
        int n = n0 + t;
        float deg = total + gam * ws[AD_W + (b << 10) + n] + 1.0f;
        ws[DIS_W + (b << 10) + n] = rsqrtf(deg + 1e-5f);
    }
    int zi = (b << 14) + ((n0 + (t >> 4)) << 4) + (t & 15);
    lvzh[zi] = gam * z[zi] * (1.0f - lvzh[zi]);
    if (blockIdx.x == 0) {
        float kl = ws[PART_W + (t << 2) + 1];
        float lg = ws[PART_W + (t << 2) + 2];
        #pragma unroll
        for (int off = 32; off > 0; off >>= 1) {
            kl += __shfl_down(kl, off);
            lg += __shfl_down(lg, off);
        }
        if ((t & 63) == 0) { redk[t >> 6] = kl; redl[t >> 6] = lg; }
        __syncthreads();
        if (t == 0) {
            fin[0] = redk[0] + redk[1] + redk[2] + redk[3];
            fin[1] = redl[0] + redl[1] + redl[2] + redl[3];
            out[KLOFF] = -0.5f * fin[0];
        }
        __syncthreads();
        if (t < 16) {
            float s = 0.f;
            #pragma unroll
            for (int g = 0; g < 16; ++g) s += ws[PART_W + (((t << 4) + g) << 2)];
            float gm = sqrtf(1.0f + 1024.0f / (s + 1e-7f));
            ws[GAM_W + t] = gm;
            out[DLOFF + t] = -gm * fin[1] / 16777216.0f;
        }
    }
}

// ---- K5: LA via MFMA on bf16 z16: LA[b,n,m] = dis_n*dis_m*(relu(zz^T)+diag)
// grid 4096 = (b, 64x64 tile); block 256 = 4 waves; wave w: rows n0+w*16..+15
// One mfma_f32_16x16x32_bf16 per 16x16 tile (K=16 real, upper 16 zero-padded)
__global__ __launch_bounds__(256) void la_kernel(const float* __restrict__ ws,
        float* __restrict__ LA)
{
    __shared__ float dan[64], dbm[64], sAd[64];
    const unsigned short* z16 = (const unsigned short*)(ws + Z16F);
    int b    = blockIdx.x >> 8;
    int tile = blockIdx.x & 255;
    int n0 = (tile >> 4) * 64;
    int m0 = (tile & 15) * 64;
    int t  = threadIdx.x;
    int w  = t >> 6, l = t & 63;
    const float* dis = ws + DIS_W + (b << 10);
    if (t < 64)       dan[t]      = dis[n0 + t];
    else if (t < 128) dbm[t - 64] = dis[m0 + (t - 64)];
    else if (t < 192) sAd[t - 128] = (n0 == m0) ? ws[AD_W + (b << 10) + n0 + (t - 128)] : 0.0f;
    __syncthreads();
    float g = ws[GAM_W + b];
    const unsigned short* zb = z16 + (b << 14);
    int rn = n0 + (w << 4);
    int lo = l & 15, hi = l >> 4;
    short8 afrag = {0,0,0,0,0,0,0,0};
    if (l < 32) afrag = *(const short8*)&zb[((rn + lo) << 4) + (hi << 3)];
    #pragma unroll
    for (int j = 0; j < 4; ++j) {
        int rm = m0 + (j << 4);
        short8 bfrag = {0,0,0,0,0,0,0,0};
        if (l < 32) bfrag = *(const short8*)&zb[((rm + lo) << 4) + (hi << 3)];
        f32x4 d = {0.f, 0.f, 0.f, 0.f};
        d = __builtin_amdgcn_mfma_f32_16x16x32_bf16(afrag, bfrag, d, 0, 0, 0);
        // lane l holds D[row=hi*4+jj][col=lo] of this 16x16 tile
        int c = rm + lo;
        float dm = dbm[(j << 4) + lo];
        #pragma unroll
        for (int jj = 0; jj < 4; ++jj) {
            int r = rn + (hi << 2) + jj;
            float v = fmaxf(d[jj], 0.f);
            if (r == c) v += g * sAd[r - n0] + 1.0f;
            float dn = dan[(w << 4) + (hi << 2) + jj];
            LA[((size_t)b << 20) + ((size_t)r << 10) + c] = dn * dm * v;
        }
    }
}

extern "C" void kernel_launch(void* const* d_in, const int* in_sizes, int n_in,
                              void* d_out, int out_size, void* d_ws, size_t ws_size,
                              hipStream_t stream) {
    const float* feature = (const float*)d_in[0];
    const float* mu_w    = (const float*)d_in[1];
    const float* mu_b    = (const float*)d_in[2];
    const float* lv_w    = (const float*)d_in[3];
    const float* lv_b    = (const float*)d_in[4];
    float* out = (float*)d_out;
    float* ws  = (float*)d_ws;
    unsigned short* nT   = (unsigned short*)d_out;          // LA region scratch
    unsigned short* apk  = nT + APK_U;
    unsigned short* lvpk = nT + LVPK_U;
    unsigned short* pmu16 = (unsigned short*)(ws + PMU_W);
    unsigned short* plv16 = (unsigned short*)(ws + PLV_W);

    pool_tr_kernel<<<8192, 256, 0, stream>>>(feature, nT, mu_w, lv_w, apk, lvpk);
    conv_mfma<<<1024, 256, 0, stream>>>(nT, apk, lvpk, pmu16, plv16);
    stats_kernel<<<256, 256, 0, stream>>>(pmu16, plv16, mu_b, lv_b,
                                          out + ZOFF, out + ZHOFF, ws);
    deg_kernel<<<1024, 256, 0, stream>>>(out + ZOFF, out + ZHOFF, ws, out);
    la_kernel<<<4096, 256, 0, stream>>>(ws, out);
}

// Round 13
// 111.737 us; speedup vs baseline: 1.3319x; 1.1494x over previous
//
#include <hip/hip_runtime.h>

typedef short short8 __attribute__((ext_vector_type(8)));
typedef float f32x4 __attribute__((ext_vector_type(4)));
typedef unsigned short ushort4v __attribute__((ext_vector_type(4)));

// ---- problem constants ----
// B=16, C=1024, H=W=64, nodes 32x32, N=1024, HID=16
// d_out float offsets
#define ZOFF   16777216   // z   (B*N*HID = 262144)  == mu flat (with bias)
#define ZHOFF  17039360   // z_hat (262144)          == log_var temp, then z_hat
#define KLOFF  17301504   // kl scalar
#define DLOFF  17301505   // dl (16)
// d_out ushort offsets (scratch inside LA region, dead before la_kernel)
#define APK_U  16777216   // Apk bf16 [9][32][64][8] = 147,456
#define LVPK_U 16924672   // lvpk bf16 [32][64][8] = 16,384
// ws float offsets
#define AD_W   0          // Ad[B*N] = 16384
#define DIS_W  16384      // dis[B*N]
#define PART_W 32768      // 256 blocks x 4 floats: sigma,kl,lg partials
#define GAM_W  34816      // gamma[16]
#define PMU_W  65536      // mu partials bf16 [8][16][16][1024]
#define PLV_W  2162688    // lv partials bf16, same extent
#define Z16F   3211264    // z bf16 copy [16][1024][16] = 262,144 ushorts

__device__ __forceinline__ unsigned short f2bf(float f) {
    unsigned int u = __float_as_uint(f);
    unsigned int r = (u + 0x7fffu + ((u >> 16) & 1u)) >> 16;
    return (unsigned short)r;
}
__device__ __forceinline__ float bf2f(unsigned short u) {
    return __uint_as_float(((unsigned int)u) << 16);
}

// ---- K1: fused 2x2 mean pool + transpose (+ weight prep in blocks <640) ----
__global__ __launch_bounds__(256) void pool_tr_kernel(const float* __restrict__ f,
        unsigned short* __restrict__ nT, const float* __restrict__ mu_w,
        const float* __restrict__ lv_w, unsigned short* __restrict__ apk,
        unsigned short* __restrict__ lvpk)
{
    __shared__ float pls[64 * 35];
    int blk = blockIdx.x;
    int b  = blk >> 9;
    int y  = (blk >> 4) & 31;
    int cb = blk & 15;
    int t  = threadIdx.x;
    int rr  = (t >> 4) & 1;
    int c16 = t & 15;
    int cho = t >> 5;
    #pragma unroll
    for (int k = 0; k < 8; ++k) {
        int ch = (k << 3) + cho;
        float4 v = ((const float4*)f)[
            ((((b << 10) + (cb << 6) + ch) << 6) + (y << 1) + rr) * 16 + c16];
        float h0 = v.x + v.y, h1 = v.z + v.w;
        float g0 = h0 + __shfl_xor(h0, 16);
        float g1 = h1 + __shfl_xor(h1, 16);
        if (rr == 0) {
            pls[ch * 35 + (c16 << 1)]     = 0.25f * g0;
            pls[ch * 35 + (c16 << 1) + 1] = 0.25f * g1;
        }
    }
    __syncthreads();
    int px = t >> 3, cg2 = t & 7;
    unsigned short o8[8];
    #pragma unroll
    for (int i = 0; i < 8; ++i) o8[i] = f2bf(pls[((cg2 << 3) + i) * 35 + px]);
    int ofs = ((((b << 10) + (y << 5) + px)) << 10) + (cb << 6) + (cg2 << 3);
    *(short8*)&nT[ofs] = *(short8*)o8;

    if (blk < 640) {                          // fused weight prep
        int idx = blk * 256 + t;
        if (idx < 147456) {
            int tap = idx >> 14;
            int rem = idx & 16383;
            int ks = rem >> 9;
            int lane = (rem >> 3) & 63;
            int j = idx & 7;
            int o = lane & 15;
            int cc = (ks << 5) + ((lane >> 4) << 3) + j;
            apk[idx] = f2bf(mu_w[((o << 10) + cc) * 9 + tap]);
        } else {
            int i2 = idx - 147456;
            int ks = i2 >> 9;
            int lane = (i2 >> 3) & 63;
            int j = i2 & 7;
            int o = lane & 15;
            int cc = (ks << 5) + ((lane >> 4) << 3) + j;
            lvpk[i2] = f2bf(lv_w[(o << 10) + cc]);
        }
    }
}

// ---- K2: MFMA conv split-K partials (bf16 out): mu (3x3 SAME) + lv (1x1) ----
// grid 1024 = b(16) x ytile(8: 4 rows) x kchunk(8: 128 ch); block 256 = 4 waves
__global__ __launch_bounds__(256) void conv_mfma(const unsigned short* __restrict__ nT,
        const unsigned short* __restrict__ apk, const unsigned short* __restrict__ lvpk,
        unsigned short* __restrict__ pmu, unsigned short* __restrict__ plv)
{
    __shared__ unsigned short st[6 * 34 * 40];   // stride 80B = 5 quads
    int blk = blockIdx.x;
    int b  = blk >> 6;
    int yt = (blk >> 3) & 7;
    int kc = blk & 7;
    int y0 = yt << 2;
    int t  = threadIdx.x;
    int w  = t >> 6, l = t & 63;
    int px = l & 15, chg = l >> 4;
    f32x4 accm[2] = {{0,0,0,0},{0,0,0,0}};
    f32x4 accv[2] = {{0,0,0,0},{0,0,0,0}};

    if (t < 48) {                                 // x-halo zeros: 6 rows x 2 x 4
        int row = t >> 3, side = (t >> 2) & 1, quarter = t & 3;
        short8 z8 = {0,0,0,0,0,0,0,0};
        *(short8*)&st[(row * 34 + side * 33) * 40 + quarter * 8] = z8;
    }

    for (int s = 0; s < 4; ++s) {
        int ksg = (kc << 2) + s;
        int cs  = ksg << 5;
        __syncthreads();
        #pragma unroll
        for (int k2 = 0; k2 < 3; ++k2) {          // stage 6 rows x 32 x x 32 ch
            int q = t + (k2 << 8);
            int quarter = q & 3, x = (q >> 2) & 31, row = q >> 7;
            int yin = y0 - 1 + row;
            short8 v = {0,0,0,0,0,0,0,0};
            if (yin >= 0 && yin < 32)
                v = *(const short8*)&nT[(((b << 10) + (yin << 5) + x) << 10) + cs + quarter * 8];
            *(short8*)&st[(row * 34 + x + 1) * 40 + quarter * 8] = v;
        }
        __syncthreads();
        short8 bw[9], bvw;
        #pragma unroll
        for (int tap = 0; tap < 9; ++tap)
            bw[tap] = *(const short8*)&apk[((tap << 5) + ksg) * 512 + l * 8];
        bvw = *(const short8*)&lvpk[(ksg << 9) + l * 8];
        #pragma unroll
        for (int h = 0; h < 2; ++h) {
            short8 actr;
            #pragma unroll
            for (int ky = 0; ky < 3; ++ky) {
                int row = w + ky;
                #pragma unroll
                for (int kx = 0; kx < 3; ++kx) {
                    int xx = (h << 4) + px + kx;
                    short8 a = *(const short8*)&st[(row * 34 + xx) * 40 + chg * 8];
                    if (ky == 1 && kx == 1) actr = a;
                    accm[h] = __builtin_amdgcn_mfma_f32_16x16x32_bf16(a, bw[ky*3+kx], accm[h], 0, 0, 0);
                }
            }
            accv[h] = __builtin_amdgcn_mfma_f32_16x16x32_bf16(actr, bvw, accv[h], 0, 0, 0);
        }
    }
    int o = px;
    #pragma unroll
    for (int h = 0; h < 2; ++h) {
        int x = (h << 4) + (chg << 2);
        int idx = (((kc << 4) + b) << 14) + (o << 10) + ((y0 + w) << 5) + x;
        ushort4v m16, v16;
        #pragma unroll
        for (int j = 0; j < 4; ++j) { m16[j] = f2bf(accm[h][j]); v16[j] = f2bf(accv[h][j]); }
        *(ushort4v*)&pmu[idx] = m16;
        *(ushort4v*)&plv[idx] = v16;
    }
}

// ---- K3: combine split-K (bf16) + bias -> z/lv (+z16); Ad, block partials --
// grid 256 = b(16) x ng(16: 64 nodes)
__global__ __launch_bounds__(256) void stats_kernel(const unsigned short* __restrict__ pmu,
        const unsigned short* __restrict__ plv, const float* __restrict__ mu_b,
        const float* __restrict__ lv_b, float* __restrict__ z,
        float* __restrict__ lvout, float* __restrict__ ws)
{
    __shared__ float smu[16 * 68], slv[16 * 68];
    __shared__ float red[3][4];
    unsigned short* z16 = (unsigned short*)(ws + Z16F);
    int blk = blockIdx.x;
    int b = blk >> 4, ng = blk & 15;
    int t = threadIdx.x;
    {
        int o = t >> 4, f4c = t & 15;
        int base = (b << 14) + (o << 10) + (ng << 6) + (f4c << 2);
        f32x4 m = {0,0,0,0}, lv = {0,0,0,0};
        #pragma unroll
        for (int kc = 0; kc < 8; ++kc) {
            ushort4v mu16 = *(const ushort4v*)(pmu + (kc << 18) + base);
            ushort4v lv16 = *(const ushort4v*)(plv + (kc << 18) + base);
            #pragma unroll
            for (int c = 0; c < 4; ++c) {
                m[c]  += bf2f(mu16[c]);
                lv[c] += bf2f(lv16[c]);
            }
        }
        float mb = mu_b[o], lb = lv_b[o];
        #pragma unroll
        for (int c = 0; c < 4; ++c) {
            smu[o * 68 + (f4c << 2) + c] = m[c] + mb;
            slv[o * 68 + (f4c << 2) + c] = lv[c] + lb;
        }
    }
    __syncthreads();
    int node2 = t >> 2, og = t & 3;
    f32x4 zm, zl;
    float ad = 0.f, klp = 0.f;
    #pragma unroll
    for (int c = 0; c < 4; ++c) {
        float mm = smu[((og << 2) + c) * 68 + node2];
        float ll = slv[((og << 2) + c) * 68 + node2];
        zm[c] = mm; zl[c] = ll;
        ad  += mm * mm;
        klp += 1.0f + 2.0f * ll - mm * mm - expf(2.0f * ll);
    }
    int zofs = (b << 14) + (((ng << 6) + node2) << 4) + (og << 2);
    *(f32x4*)(z + zofs)     = zm;
    *(f32x4*)(lvout + zofs) = zl;
    ushort4v z16v;
    #pragma unroll
    for (int c = 0; c < 4; ++c) z16v[c] = f2bf(zm[c]);
    *(ushort4v*)&z16[zofs] = z16v;
    ad  += __shfl_xor(ad, 1);  ad  += __shfl_xor(ad, 2);
    klp += __shfl_xor(klp, 1); klp += __shfl_xor(klp, 2);
    float lg = logf(ad + 1e-7f);
    if (og == 0) ws[AD_W + (b << 10) + (ng << 6) + node2] = ad;
    float sgc = (og == 0) ? ad  : 0.f;
    float klc = (og == 0) ? klp : 0.f;
    float lgc = (og == 0) ? lg  : 0.f;
    #pragma unroll
    for (int off = 32; off > 0; off >>= 1) {
        sgc += __shfl_down(sgc, off);
        klc += __shfl_down(klc, off);
        lgc += __shfl_down(lgc, off);
    }
    int wv = t >> 6;
    if ((t & 63) == 0) { red[0][wv] = sgc; red[1][wv] = klc; red[2][wv] = lgc; }
    __syncthreads();
    if (t == 0) {
        ws[PART_W + (blk << 2) + 0] = red[0][0] + red[0][1] + red[0][2] + red[0][3];
        ws[PART_W + (blk << 2) + 1] = red[1][0] + red[1][1] + red[1][2] + red[1][3];
        ws[PART_W + (blk << 2) + 2] = red[2][0] + red[2][1] + red[2][2] + red[2][3];
    }
}

// ---- K4: deg via MFMA row sums of relu(zz^T); fused gamma/z_hat/kl/dl ------
// grid 256 = b(16) x ntile(16: 64 rows); block 256 = 4 waves, wave w: 16 rows
__global__ __launch_bounds__(256) void deg_kernel(const float* __restrict__ z,
        float* __restrict__ lvzh, float* __restrict__ ws, float* __restrict__ out)
{
    __shared__ float redk[4], redl[4], fin[2];
    const unsigned short* z16 = (const unsigned short*)(ws + Z16F);
    int blk = blockIdx.x;
    int b  = blk >> 4;
    int n0 = (blk & 15) << 6;
    int t  = threadIdx.x;
    int w  = t >> 6, l = t & 63;
    int lo = l & 15, hi = l >> 4;
    float sg16 = 0.f;
    #pragma unroll
    for (int g = 0; g < 16; ++g) sg16 += ws[PART_W + (((b << 4) + g) << 2)];
    float gam = sqrtf(1.0f + 1024.0f / (sg16 + 1e-7f));
    // z_hat: 4 contiguous 256-elem sweeps over rows n0..n0+63
    #pragma unroll
    for (int e = 0; e < 4; ++e) {
        int zi = (b << 14) + (n0 << 4) + (e << 8) + t;
        lvzh[zi] = gam * z[zi] * (1.0f - lvzh[zi]);
    }
    // row sums: wave w owns rows rn..rn+15
    const unsigned short* zb = z16 + (b << 14);
    int rn = n0 + (w << 4);
    short8 afrag = {0,0,0,0,0,0,0,0};
    if (l < 32) afrag = *(const short8*)&zb[((rn + lo) << 4) + (hi << 3)];
    f32x4 rs = {0.f, 0.f, 0.f, 0.f};
    #pragma unroll 4
    for (int mt = 0; mt < 64; ++mt) {
        short8 bfrag = {0,0,0,0,0,0,0,0};
        if (l < 32) bfrag = *(const short8*)&zb[(((mt << 4) + lo) << 4) + (hi << 3)];
        f32x4 d = {0.f, 0.f, 0.f, 0.f};
        d = __builtin_amdgcn_mfma_f32_16x16x32_bf16(afrag, bfrag, d, 0, 0, 0);
        #pragma unroll
        for (int jj = 0; jj < 4; ++jj) rs[jj] += fmaxf(d[jj], 0.f);
    }
    #pragma unroll
    for (int m = 1; m < 16; m <<= 1) {
        #pragma unroll
        for (int jj = 0; jj < 4; ++jj) rs[jj] += __shfl_xor(rs[jj], m);
    }
    if (lo == 0) {
        #pragma unroll
        for (int jj = 0; jj < 4; ++jj) {
            int n = rn + (hi << 2) + jj;
            float deg = rs[jj] + gam * ws[AD_W + (b << 10) + n] + 1.0f;
            ws[DIS_W + (b << 10) + n] = rsqrtf(deg + 1e-5f);
        }
    }
    if (blk == 0) {
        float kl = ws[PART_W + (t << 2) + 1];
        float lg = ws[PART_W + (t << 2) + 2];
        #pragma unroll
        for (int off = 32; off > 0; off >>= 1) {
            kl += __shfl_down(kl, off);
            lg += __shfl_down(lg, off);
        }
        if ((t & 63) == 0) { redk[t >> 6] = kl; redl[t >> 6] = lg; }
        __syncthreads();
        if (t == 0) {
            fin[0] = redk[0] + redk[1] + redk[2] + redk[3];
            fin[1] = redl[0] + redl[1] + redl[2] + redl[3];
            out[KLOFF] = -0.5f * fin[0];
        }
        __syncthreads();
        if (t < 16) {
            float s = 0.f;
            #pragma unroll
            for (int g = 0; g < 16; ++g) s += ws[PART_W + (((t << 4) + g) << 2)];
            float gm = sqrtf(1.0f + 1024.0f / (s + 1e-7f));
            ws[GAM_W + t] = gm;
            out[DLOFF + t] = -gm * fin[1] / 16777216.0f;
        }
    }
}

// ---- K5: LA via MFMA on bf16 z16: LA[b,n,m] = dis_n*dis_m*(relu(zz^T)+diag)
__global__ __launch_bounds__(256) void la_kernel(const float* __restrict__ ws,
        float* __restrict__ LA)
{
    __shared__ float dan[64], dbm[64], sAd[64];
    const unsigned short* z16 = (const unsigned short*)(ws + Z16F);
    int b    = blockIdx.x >> 8;
    int tile = blockIdx.x & 255;
    int n0 = (tile >> 4) * 64;
    int m0 = (tile & 15) * 64;
    int t  = threadIdx.x;
    int w  = t >> 6, l = t & 63;
    const float* dis = ws + DIS_W + (b << 10);
    if (t < 64)       dan[t]      = dis[n0 + t];
    else if (t < 128) dbm[t - 64] = dis[m0 + (t - 64)];
    else if (t < 192) sAd[t - 128] = (n0 == m0) ? ws[AD_W + (b << 10) + n0 + (t - 128)] : 0.0f;
    __syncthreads();
    float g = ws[GAM_W + b];
    const unsigned short* zb = z16 + (b << 14);
    int rn = n0 + (w << 4);
    int lo = l & 15, hi = l >> 4;
    short8 afrag = {0,0,0,0,0,0,0,0};
    if (l < 32) afrag = *(const short8*)&zb[((rn + lo) << 4) + (hi << 3)];
    #pragma unroll
    for (int j = 0; j < 4; ++j) {
        int rm = m0 + (j << 4);
        short8 bfrag = {0,0,0,0,0,0,0,0};
        if (l < 32) bfrag = *(const short8*)&zb[((rm + lo) << 4) + (hi << 3)];
        f32x4 d = {0.f, 0.f, 0.f, 0.f};
        d = __builtin_amdgcn_mfma_f32_16x16x32_bf16(afrag, bfrag, d, 0, 0, 0);
        int c = rm + lo;
        float dm = dbm[(j << 4) + lo];
        #pragma unroll
        for (int jj = 0; jj < 4; ++jj) {
            int r = rn + (hi << 2) + jj;
            float v = fmaxf(d[jj], 0.f);
            if (r == c) v += g * sAd[r - n0] + 1.0f;
            float dn = dan[(w << 4) + (hi << 2) + jj];
            LA[((size_t)b << 20) + ((size_t)r << 10) + c] = dn * dm * v;
        }
    }
}

extern "C" void kernel_launch(void* const* d_in, const int* in_sizes, int n_in,
                              void* d_out, int out_size, void* d_ws, size_t ws_size,
                              hipStream_t stream) {
    const float* feature = (const float*)d_in[0];
    const float* mu_w    = (const float*)d_in[1];
    const float* mu_b    = (const float*)d_in[2];
    const float* lv_w    = (const float*)d_in[3];
    const float* lv_b    = (const float*)d_in[4];
    float* out = (float*)d_out;
    float* ws  = (float*)d_ws;
    unsigned short* nT   = (unsigned short*)d_out;          // LA region scratch
    unsigned short* apk  = nT + APK_U;
    unsigned short* lvpk = nT + LVPK_U;
    unsigned short* pmu16 = (unsigned short*)(ws + PMU_W);
    unsigned short* plv16 = (unsigned short*)(ws + PLV_W);

    pool_tr_kernel<<<8192, 256, 0, stream>>>(feature, nT, mu_w, lv_w, apk, lvpk);
    conv_mfma<<<1024, 256, 0, stream>>>(nT, apk, lvpk, pmu16, plv16);
    stats_kernel<<<256, 256, 0, stream>>>(pmu16, plv16, mu_b, lv_b,
                                          out + ZOFF, out + ZHOFF, ws);
    deg_kernel<<<256, 256, 0, stream>>>(out + ZOFF, out + ZHOFF, ws, out);
    la_kernel<<<4096, 256, 0, stream>>>(ws, out);
}